// Round 7
// baseline (420.566 us; speedup 1.0000x reference)
//
#include <hip/hip_runtime.h>

// MultiHeadAttention B=16 N=1024 E=768 H=8 D=96 — fp16 MFMA pipeline.
// ws layout (130.6 MB total):
//   WT   [3072][768] fp16 : rows 0-2303 = (Wq|Wk|Wv)^T, rows 2304-3071 = Wo^T
//   bias [2304] f32
//   xh   [16384][768] fp16
//   QKV  [16384][2304] fp16 (cols: 0-767 Q, 768-1535 K, 1536-2303 V; head h at h*96)
//   Oh   [16384][768] fp16 (attention output, pre-projection)

typedef _Float16 half8 __attribute__((ext_vector_type(8)));
typedef __fp16 fp16x2 __attribute__((ext_vector_type(2)));
typedef float f32x4 __attribute__((ext_vector_type(4)));
typedef float f32x16 __attribute__((ext_vector_type(16)));

__device__ __forceinline__ void gload_lds16(const void* g, void* l) {
  __builtin_amdgcn_global_load_lds((const __attribute__((address_space(1))) void*)g,
                                   (__attribute__((address_space(3))) void*)l, 16, 0, 0);
}

// ---------------- converts ----------------

__global__ __launch_bounds__(256) void conv_x_kernel(const float* __restrict__ x,
                                                     _Float16* __restrict__ xh) {
  long i = ((long)blockIdx.x * 256 + threadIdx.x) * 8;
  float4 a = *(const float4*)(x + i);
  float4 b = *(const float4*)(x + i + 4);
  half8 o;
  o[0] = (_Float16)a.x; o[1] = (_Float16)a.y; o[2] = (_Float16)a.z; o[3] = (_Float16)a.w;
  o[4] = (_Float16)b.x; o[5] = (_Float16)b.y; o[6] = (_Float16)b.z; o[7] = (_Float16)b.w;
  *(half8*)(xh + i) = o;
}

__global__ __launch_bounds__(256) void transpose_cvt_kernel(
    const float* __restrict__ W0, const float* __restrict__ W1,
    const float* __restrict__ W2, const float* __restrict__ W3,
    _Float16* __restrict__ WT) {
  __shared__ float tile[32][33];
  int z = blockIdx.z;
  const float* W = (z == 0) ? W0 : (z == 1) ? W1 : (z == 2) ? W2 : W3;
  int k0 = blockIdx.y * 32, n0 = blockIdx.x * 32;
  int tx = threadIdx.x, ty = threadIdx.y;
#pragma unroll
  for (int j = ty; j < 32; j += 8)
    tile[j][tx] = W[(size_t)(k0 + j) * 768 + n0 + tx];
  __syncthreads();
  _Float16* dst = WT + (size_t)z * 768 * 768;
#pragma unroll
  for (int j = ty; j < 32; j += 8)
    dst[(size_t)(n0 + j) * 768 + k0 + tx] = (_Float16)tile[tx][j];
}

__global__ __launch_bounds__(256) void conv_bias_kernel(const float* __restrict__ bq,
                                                        const float* __restrict__ bk,
                                                        const float* __restrict__ bv,
                                                        float* __restrict__ bias) {
  int i = blockIdx.x * 256 + threadIdx.x;
  if (i >= 2304) return;
  bias[i] = (i < 768) ? bq[i] : (i < 1536) ? bk[i - 768] : bv[i - 1536];
}

// ------- GEMM 256x256, BK=64, 8 waves (2M x 4N), counted-vmcnt double buffer -------

template <int OUT_F16>
__global__ __launch_bounds__(512, 2) void gemm256_kernel(
    const _Float16* __restrict__ A, const _Float16* __restrict__ Bt,
    const float* __restrict__ bias, void* __restrict__ C,
    int M, int N, int K, int ldc) {
  __shared__ _Float16 As[2][256 * 64];
  __shared__ _Float16 Bs[2][256 * 64];
  int nbx = N >> 8;
  int nwg = gridDim.x, wg = blockIdx.x;
  int cpx = nwg >> 3;
  int swz = (wg & 7) * cpx + (wg >> 3);
  int bx = swz % nbx, by = swz / nbx;
  int m0 = by * 256, n0 = bx * 256;
  int t = threadIdx.x, l = t & 63, w = t >> 6;
  int lg = l >> 4, lr = l & 15;
  int wr = w >> 2, wc = w & 3;
  f32x4 acc[8][4] = {};

  int srow[4], ssc[4];
#pragma unroll
  for (int j = 0; j < 4; ++j) {
    int slot = j * 512 + t;
    srow[j] = slot >> 3;
    ssc[j] = ((slot & 7) ^ (srow[j] & 7)) * 8;
  }

  auto stage = [&](int kt, int bi) {
    int k0 = kt * 64;
#pragma unroll
    for (int j = 0; j < 4; ++j)
      gload_lds16(A + (size_t)(m0 + srow[j]) * K + k0 + ssc[j], &As[bi][(j * 512 + t) * 8]);
#pragma unroll
    for (int j = 0; j < 4; ++j)
      gload_lds16(Bt + (size_t)(n0 + srow[j]) * K + k0 + ssc[j], &Bs[bi][(j * 512 + t) * 8]);
  };

  auto compute = [&](int bi) {
#pragma unroll
    for (int kk = 0; kk < 2; ++kk) {
      half8 bf[4];
#pragma unroll
      for (int nf = 0; nf < 4; ++nf) {
        int row = wc * 64 + nf * 16 + lr;
        bf[nf] = *(const half8*)&Bs[bi][row * 64 + ((kk * 4 + lg) ^ (row & 7)) * 8];
      }
#pragma unroll
      for (int mf = 0; mf < 8; ++mf) {
        int row = wr * 128 + mf * 16 + lr;
        half8 af = *(const half8*)&As[bi][row * 64 + ((kk * 4 + lg) ^ (row & 7)) * 8];
#pragma unroll
        for (int nf = 0; nf < 4; ++nf)
          acc[mf][nf] = __builtin_amdgcn_mfma_f32_16x16x32_f16(af, bf[nf], acc[mf][nf], 0, 0, 0);
      }
    }
  };

  int nkt = K >> 6;
  stage(0, 0);
  for (int kt = 0; kt < nkt; ++kt) {
    int bi = kt & 1;
    if (kt + 1 < nkt) {
      stage(kt + 1, bi ^ 1);
      asm volatile("s_waitcnt vmcnt(8)" ::: "memory");
    } else {
      asm volatile("s_waitcnt vmcnt(0)" ::: "memory");
    }
    __builtin_amdgcn_sched_barrier(0);
    __builtin_amdgcn_s_barrier();
    __builtin_amdgcn_sched_barrier(0);
    compute(bi);
    __builtin_amdgcn_sched_barrier(0);
    __builtin_amdgcn_s_barrier();
  }

#pragma unroll
  for (int mf = 0; mf < 8; ++mf)
#pragma unroll
    for (int nf = 0; nf < 4; ++nf) {
      int col = n0 + wc * 64 + nf * 16 + lr;
      float bb = bias[col];
#pragma unroll
      for (int i = 0; i < 4; ++i) {
        int row = m0 + wr * 128 + mf * 16 + lg * 4 + i;
        float v = acc[mf][nf][i] + bb;
        if (OUT_F16)
          ((_Float16*)C)[(size_t)row * ldc + col] = (_Float16)v;
        else
          ((float*)C)[(size_t)row * ldc + col] = v;
      }
    }
}

// ---------------- flash attention: 32x32 MFMA, in-register P ----------------
// Grid 1024 (XCD-chunked lin), 256 thr = 4 waves; wave owns 32 q rows (QBLK=128).
// KVBLK=64, double-buffered. LDS 48KB:
//   KF [2][12 frag][64 lane][16B]: K in 32x32 A-frag order (kv=sb*32+(l&31),
//       d=c*16+(l>>5)*8) staged linearly via global_load_lds -> reads conflict-free.
//   VF [2][96 d][64 kv]: R4-proven scatter layout, kv-chunk XOR ((d&7)^((d>>3)&7)).
// Swapped QK^T: S^T[kv][q] = mfma(K,Q); D: col=l&31=q, row kv=(reg&3)+8(reg>>2)+4hi.
// Softmax in-lane (32 vals) + 1 shfl_xor(32); P->fp16 via cvt_pkrtz, PV A-frags
// assembled with 8 shfl_xor(32) (lane<->lane^32 exchange) — NO P in LDS.
// Q pre-scaled by LOG2E; defer-max THR=11.5; O /= (l_run*sqrt(768)).

__global__ __launch_bounds__(256, 2) void attn_kernel(const _Float16* __restrict__ QKV,
                                                      _Float16* __restrict__ Oh) {
  int hw = blockIdx.x;
  int lin = (hw & 7) * 128 + (hw >> 3);   // XCD-chunked
  int bh = lin >> 3, qt = lin & 7;
  int b = bh >> 3, h = bh & 7;
  int t = threadIdx.x, w = t >> 6, l = t & 63;
  int lr = l & 31, hi = l >> 5;

  __shared__ __align__(16) char KF[2][12288];
  __shared__ __align__(16) _Float16 VF[2][96 * 64];

  const _Float16* Qb = QKV + (size_t)b * 1024 * 2304 + h * 96;
  const _Float16* Kb = Qb + 768;
  const _Float16* Vb = Qb + 1536;

  // Q fragments (B-operand): lane holds Q[q = qt*128+w*32+lr][d = c*16+hi*8 .. +7]
  half8 qf[6];
  {
    int qrow = qt * 128 + w * 32 + lr;
    const _Float16 s = (_Float16)1.4426950408889634f;  // LOG2E folded into Q
#pragma unroll
    for (int c = 0; c < 6; ++c) {
      qf[c] = *(const half8*)&Qb[(size_t)qrow * 2304 + c * 16 + hi * 8];
#pragma unroll
      for (int e = 0; e < 8; ++e) qf[c][e] = qf[c][e] * s;
    }
  }

  // ---- hoisted staging offsets ----
  // K: 768 slots (12 frags x 64 lanes), 3 per thread
  int ks_src[3], ks_dst[3];
#pragma unroll
  for (int j = 0; j < 3; ++j) {
    int s = j * 256 + t;
    int f = s >> 6, lane = s & 63;
    int sb = f / 6, c = f - sb * 6;
    ks_src[j] = (sb * 32 + (lane & 31)) * 2304 + c * 16 + ((lane >> 5) & 1) * 8;
    ks_dst[j] = s * 16;
  }
  // V: 384 units (32 kv-pairs x 12 d-chunks), reg-transpose scatter (R4-proven)
  bool vact[2];
  int v_src[2], v_dst[2][8];
#pragma unroll
  for (int j = 0; j < 2; ++j) {
    int u = j * 256 + t;
    vact[j] = u < 384;
    int kvp = u / 12, mm = u % 12;
    v_src[j] = 2 * kvp * 2304 + mm * 8;
#pragma unroll
    for (int e = 0; e < 8; ++e) {
      int d = mm * 8 + e;
      int sw = ((d & 7) ^ ((d >> 3) & 7)) << 3;
      v_dst[j][e] = d * 64 + ((2 * kvp) ^ sw);
    }
  }

  auto stage = [&](int kv0, int bi) {
    size_t goff = (size_t)kv0 * 2304;
#pragma unroll
    for (int j = 0; j < 3; ++j)
      gload_lds16(Kb + goff + ks_src[j], &KF[bi][ks_dst[j]]);
#pragma unroll
    for (int j = 0; j < 2; ++j)
      if (vact[j]) {
        const _Float16* vp = Vb + goff + v_src[j];
        half8 v0 = *(const half8*)vp;
        half8 v1 = *(const half8*)(vp + 2304);
#pragma unroll
        for (int e = 0; e < 8; ++e) {
          union { _Float16 h2[2]; unsigned u32; } pk;
          pk.h2[0] = v0[e]; pk.h2[1] = v1[e];
          *(unsigned*)&VF[bi][v_dst[j][e]] = pk.u32;
        }
      }
  };

  float m_run = -3.0e38f, l_run = 0.f;
  f32x16 oa[3] = {};  // O: col d = dt*32+lr, row q = (reg&3)+8*(reg>>2)+4*hi

  stage(0, 0);

  for (int tile = 0; tile < 16; ++tile) {
    int bi = tile & 1;
    __syncthreads();  // stage(tile) resident; compute(tile-1) done
    if (tile + 1 < 16) stage((tile + 1) * 64, bi ^ 1);

    // --- QK^T: S^T sub-tiles (kv subtile sb of 32) x full d=96
    f32x16 sA[2] = {};
#pragma unroll
    for (int sb = 0; sb < 2; ++sb)
#pragma unroll
      for (int c = 0; c < 6; ++c) {
        half8 kf = *(const half8*)(KF[bi] + (sb * 6 + c) * 1024 + l * 16);
        sA[sb] = __builtin_amdgcn_mfma_f32_32x32x16_f16(kf, qf[c], sA[sb], 0, 0, 0);
      }

    // --- softmax (log2 domain); lane owns q = lr; 32 vals in-lane + partner
    float tmax = -3.0e38f;
#pragma unroll
    for (int sb = 0; sb < 2; ++sb)
#pragma unroll
      for (int r = 0; r < 16; ++r) tmax = fmaxf(tmax, sA[sb][r]);
    tmax = fmaxf(tmax, __shfl_xor(tmax, 32, 64));

    if (!__all(tmax <= m_run + 11.5f)) {   // defer-max
      float m_new = fmaxf(m_run, tmax);
      float scale = __builtin_exp2f(m_run - m_new);
#pragma unroll
      for (int r = 0; r < 16; ++r) {
        float sr = __shfl(scale, (r & 3) + 8 * (r >> 2) + 4 * hi, 64);
        oa[0][r] *= sr; oa[1][r] *= sr; oa[2][r] *= sr;
      }
      l_run *= scale;
      m_run = m_new;
    }

    // --- P = exp2(S-m): pack keep (regs +4*hi) and send (regs +4*(1-hi)) words
    unsigned keep[8], send[8];  // idx = sb*4 + kb*2 + m
    float rs = 0.f;
#pragma unroll
    for (int sb = 0; sb < 2; ++sb)
#pragma unroll
      for (int kb = 0; kb < 2; ++kb)
#pragma unroll
        for (int m = 0; m < 2; ++m) {
          int rk = 2 * m + 8 * kb + 4 * hi;
          int rq = 2 * m + 8 * kb + 4 * (1 - hi);
          float k0 = __builtin_exp2f(sA[sb][rk] - m_run);
          float k1 = __builtin_exp2f(sA[sb][rk + 1] - m_run);
          float q0 = __builtin_exp2f(sA[sb][rq] - m_run);
          float q1 = __builtin_exp2f(sA[sb][rq + 1] - m_run);
          rs += (k0 + k1) + (q0 + q1);
          union { fp16x2 h2; unsigned u; } a, bb;
          a.h2 = __builtin_amdgcn_cvt_pkrtz(k0, k1);
          bb.h2 = __builtin_amdgcn_cvt_pkrtz(q0, q1);
          keep[sb * 4 + kb * 2 + m] = a.u;
          send[sb * 4 + kb * 2 + m] = bb.u;
        }
    rs += __shfl_xor(rs, 32, 64);
    l_run += rs;

    unsigned recv[8];
#pragma unroll
    for (int i = 0; i < 8; ++i) recv[i] = __shfl_xor(send[i], 32, 64);

    // --- assemble PV A-frags: pa[kstep] words wj: own if (wj>>1)==hi else recv
    // word index = (kstep>>1)*4 + (kstep&1)*2 + (wj&1)
#pragma unroll
    for (int kstep = 0; kstep < 4; ++kstep) {
      int base = (kstep >> 1) * 4 + (kstep & 1) * 2;
      union { unsigned u[4]; half8 h8; } pa;
      pa.u[0] = hi ? recv[base + 0] : keep[base + 0];
      pa.u[1] = hi ? recv[base + 1] : keep[base + 1];
      pa.u[2] = hi ? keep[base + 0] : recv[base + 0];
      pa.u[3] = hi ? keep[base + 1] : recv[base + 1];
      // --- PV: B = V frag from VF (conflict-free via d-XOR swizzle)
#pragma unroll
      for (int dt = 0; dt < 3; ++dt) {
        int d = dt * 32 + lr;
        int sw = ((d & 7) ^ ((d >> 3) & 7)) << 3;
        half8 vf = *(const half8*)&VF[bi][d * 64 + ((kstep * 16 + hi * 8) ^ sw)];
        oa[dt] = __builtin_amdgcn_mfma_f32_32x32x16_f16(pa.h8, vf, oa[dt], 0, 0, 0);
      }
    }
  }

  // --- epilogue: O /= (l_run * sqrt(768))
  float inv = 1.0f / (l_run * 27.712812921102035f);
  size_t rbase = (size_t)(b * 1024 + qt * 128 + w * 32) * 768 + h * 96;
#pragma unroll
  for (int r = 0; r < 16; ++r) {
    int q = (r & 3) + 8 * (r >> 2) + 4 * hi;
    float ivr = __shfl(inv, q, 64);
#pragma unroll
    for (int dt = 0; dt < 3; ++dt)
      Oh[rbase + (size_t)q * 768 + dt * 32 + lr] = (_Float16)(oa[dt][r] * ivr);
  }
}

// ---------------- launch ----------------

extern "C" void kernel_launch(void* const* d_in, const int* in_sizes, int n_in,
                              void* d_out, int out_size, void* d_ws, size_t ws_size,
                              hipStream_t stream) {
  const float* x  = (const float*)d_in[0];
  const float* Wq = (const float*)d_in[1];
  const float* bq = (const float*)d_in[2];
  const float* Wk = (const float*)d_in[3];
  const float* bk = (const float*)d_in[4];
  const float* Wv = (const float*)d_in[5];
  const float* bv = (const float*)d_in[6];
  const float* Wo = (const float*)d_in[7];
  const float* bo = (const float*)d_in[8];
  float* out = (float*)d_out;

  char* ws = (char*)d_ws;
  _Float16* WT   = (_Float16*)(ws);                // 4,718,592 B
  float*    bias = (float*)(ws + 4718592);         // 9,216 B (padded to 32K)
  _Float16* xh   = (_Float16*)(ws + 4751360);      // 25,165,824 B
  _Float16* QKV  = (_Float16*)(ws + 29917184);     // 75,497,472 B
  _Float16* Oh   = (_Float16*)(ws + 105414656);    // 25,165,824 B  (total ~130.6 MB)

  conv_x_kernel<<<6144, 256, 0, stream>>>(x, xh);
  transpose_cvt_kernel<<<dim3(24, 24, 4), dim3(32, 8), 0, stream>>>(Wq, Wk, Wv, Wo, WT);
  conv_bias_kernel<<<9, 256, 0, stream>>>(bq, bk, bv, bias);

  // QKV: M=16384, N=2304, K=768 -> grid 64*9 = 576 (div by 8 for XCD swizzle)
  gemm256_kernel<1><<<576, 512, 0, stream>>>(xh, WT, bias, QKV, 16384, 2304, 768, 2304);

  attn_kernel<<<1024, 256, 0, stream>>>(QKV, Oh);

  // out-proj: M=16384, N=768, K=768 -> grid 64*3 = 192
  gemm256_kernel<0><<<192, 512, 0, stream>>>(Oh, WT + (size_t)2304 * 768, bo, out,
                                             16384, 768, 768, 768);
}

// Round 8
// 235.424 us; speedup vs baseline: 1.7864x; 1.7864x over previous
//
#include <hip/hip_runtime.h>

// MultiHeadAttention B=16 N=1024 E=768 H=8 D=96 — fp16 MFMA pipeline.
// ws layout (130.6 MB total):
//   WT   [3072][768] fp16 : rows 0-2303 = (Wq|Wk|Wv)^T, rows 2304-3071 = Wo^T
//   bias [2304] f32
//   xh   [16384][768] fp16
//   QKV  [16384][2304] fp16 (cols: 0-767 Q, 768-1535 K, 1536-2303 V; head h at h*96)
//   Oh   [16384][768] fp16 (attention output, pre-projection)

typedef _Float16 half8 __attribute__((ext_vector_type(8)));
typedef __fp16 fp16x2 __attribute__((ext_vector_type(2)));
typedef float f32x4 __attribute__((ext_vector_type(4)));
typedef float f32x16 __attribute__((ext_vector_type(16)));

__device__ __forceinline__ void gload_lds16(const void* g, void* l) {
  __builtin_amdgcn_global_load_lds((const __attribute__((address_space(1))) void*)g,
                                   (__attribute__((address_space(3))) void*)l, 16, 0, 0);
}

// ---------------- converts ----------------

__global__ __launch_bounds__(256) void conv_x_kernel(const float* __restrict__ x,
                                                     _Float16* __restrict__ xh) {
  long i = ((long)blockIdx.x * 256 + threadIdx.x) * 8;
  float4 a = *(const float4*)(x + i);
  float4 b = *(const float4*)(x + i + 4);
  half8 o;
  o[0] = (_Float16)a.x; o[1] = (_Float16)a.y; o[2] = (_Float16)a.z; o[3] = (_Float16)a.w;
  o[4] = (_Float16)b.x; o[5] = (_Float16)b.y; o[6] = (_Float16)b.z; o[7] = (_Float16)b.w;
  *(half8*)(xh + i) = o;
}

__global__ __launch_bounds__(256) void transpose_cvt_kernel(
    const float* __restrict__ W0, const float* __restrict__ W1,
    const float* __restrict__ W2, const float* __restrict__ W3,
    _Float16* __restrict__ WT) {
  __shared__ float tile[32][33];
  int z = blockIdx.z;
  const float* W = (z == 0) ? W0 : (z == 1) ? W1 : (z == 2) ? W2 : W3;
  int k0 = blockIdx.y * 32, n0 = blockIdx.x * 32;
  int tx = threadIdx.x, ty = threadIdx.y;
#pragma unroll
  for (int j = ty; j < 32; j += 8)
    tile[j][tx] = W[(size_t)(k0 + j) * 768 + n0 + tx];
  __syncthreads();
  _Float16* dst = WT + (size_t)z * 768 * 768;
#pragma unroll
  for (int j = ty; j < 32; j += 8)
    dst[(size_t)(n0 + j) * 768 + k0 + tx] = (_Float16)tile[tx][j];
}

__global__ __launch_bounds__(256) void conv_bias_kernel(const float* __restrict__ bq,
                                                        const float* __restrict__ bk,
                                                        const float* __restrict__ bv,
                                                        float* __restrict__ bias) {
  int i = blockIdx.x * 256 + threadIdx.x;
  if (i >= 2304) return;
  bias[i] = (i < 768) ? bq[i] : (i < 1536) ? bk[i - 768] : bv[i - 1536];
}

// ------- GEMM 256x256, BK=64, 8 waves (2M x 4N), counted-vmcnt double buffer -------

template <int OUT_F16>
__global__ __launch_bounds__(512, 2) void gemm256_kernel(
    const _Float16* __restrict__ A, const _Float16* __restrict__ Bt,
    const float* __restrict__ bias, void* __restrict__ C,
    int M, int N, int K, int ldc) {
  __shared__ _Float16 As[2][256 * 64];
  __shared__ _Float16 Bs[2][256 * 64];
  int nbx = N >> 8;
  int nwg = gridDim.x, wg = blockIdx.x;
  int cpx = nwg >> 3;
  int swz = (wg & 7) * cpx + (wg >> 3);
  int bx = swz % nbx, by = swz / nbx;
  int m0 = by * 256, n0 = bx * 256;
  int t = threadIdx.x, l = t & 63, w = t >> 6;
  int lg = l >> 4, lr = l & 15;
  int wr = w >> 2, wc = w & 3;
  f32x4 acc[8][4] = {};

  int srow[4], ssc[4];
#pragma unroll
  for (int j = 0; j < 4; ++j) {
    int slot = j * 512 + t;
    srow[j] = slot >> 3;
    ssc[j] = ((slot & 7) ^ (srow[j] & 7)) * 8;
  }

  auto stage = [&](int kt, int bi) {
    int k0 = kt * 64;
#pragma unroll
    for (int j = 0; j < 4; ++j)
      gload_lds16(A + (size_t)(m0 + srow[j]) * K + k0 + ssc[j], &As[bi][(j * 512 + t) * 8]);
#pragma unroll
    for (int j = 0; j < 4; ++j)
      gload_lds16(Bt + (size_t)(n0 + srow[j]) * K + k0 + ssc[j], &Bs[bi][(j * 512 + t) * 8]);
  };

  auto compute = [&](int bi) {
#pragma unroll
    for (int kk = 0; kk < 2; ++kk) {
      half8 bf[4];
#pragma unroll
      for (int nf = 0; nf < 4; ++nf) {
        int row = wc * 64 + nf * 16 + lr;
        bf[nf] = *(const half8*)&Bs[bi][row * 64 + ((kk * 4 + lg) ^ (row & 7)) * 8];
      }
#pragma unroll
      for (int mf = 0; mf < 8; ++mf) {
        int row = wr * 128 + mf * 16 + lr;
        half8 af = *(const half8*)&As[bi][row * 64 + ((kk * 4 + lg) ^ (row & 7)) * 8];
#pragma unroll
        for (int nf = 0; nf < 4; ++nf)
          acc[mf][nf] = __builtin_amdgcn_mfma_f32_16x16x32_f16(af, bf[nf], acc[mf][nf], 0, 0, 0);
      }
    }
  };

  int nkt = K >> 6;
  stage(0, 0);
  for (int kt = 0; kt < nkt; ++kt) {
    int bi = kt & 1;
    if (kt + 1 < nkt) {
      stage(kt + 1, bi ^ 1);
      asm volatile("s_waitcnt vmcnt(8)" ::: "memory");
    } else {
      asm volatile("s_waitcnt vmcnt(0)" ::: "memory");
    }
    __builtin_amdgcn_sched_barrier(0);
    __builtin_amdgcn_s_barrier();
    __builtin_amdgcn_sched_barrier(0);
    compute(bi);
    __builtin_amdgcn_sched_barrier(0);
    __builtin_amdgcn_s_barrier();
  }

#pragma unroll
  for (int mf = 0; mf < 8; ++mf)
#pragma unroll
    for (int nf = 0; nf < 4; ++nf) {
      int col = n0 + wc * 64 + nf * 16 + lr;
      float bb = bias[col];
#pragma unroll
      for (int i = 0; i < 4; ++i) {
        int row = m0 + wr * 128 + mf * 16 + lg * 4 + i;
        float v = acc[mf][nf][i] + bb;
        if (OUT_F16)
          ((_Float16*)C)[(size_t)row * ldc + col] = (_Float16)v;
        else
          ((float*)C)[(size_t)row * ldc + col] = v;
      }
    }
}

// ---------------- flash attention: 32x32 MFMA, in-register P ----------------
// Grid 1024 (XCD-chunked lin), 256 thr = 4 waves; wave owns 32 q rows (QBLK=128).
// KVBLK=64, double-buffered. LDS 48KB. KF fragment-major (conflict-free b128);
// VF scatter layout with d-XOR swizzle. P stays in registers: exp2 with
// CONSTANT vector indices (rule #20), pack to dwords, keep/send derived by a
// single hi-select per packed word, lane<->lane^32 exchange via shfl_xor(32).
// Q pre-scaled by LOG2E; defer-max THR=11.5; O /= (l_run*sqrt(768)).

__global__ __launch_bounds__(256, 2) void attn_kernel(const _Float16* __restrict__ QKV,
                                                      _Float16* __restrict__ Oh) {
  int hw = blockIdx.x;
  int lin = (hw & 7) * 128 + (hw >> 3);   // XCD-chunked
  int bh = lin >> 3, qt = lin & 7;
  int b = bh >> 3, h = bh & 7;
  int t = threadIdx.x, w = t >> 6, l = t & 63;
  int lr = l & 31, hi = l >> 5;

  __shared__ __align__(16) char KF[2][12288];
  __shared__ __align__(16) _Float16 VF[2][96 * 64];

  const _Float16* Qb = QKV + (size_t)b * 1024 * 2304 + h * 96;
  const _Float16* Kb = Qb + 768;
  const _Float16* Vb = Qb + 1536;

  // Q fragments (B-operand): lane holds Q[q = qt*128+w*32+lr][d = c*16+hi*8 .. +7]
  half8 qf[6];
  {
    int qrow = qt * 128 + w * 32 + lr;
    const _Float16 s = (_Float16)1.4426950408889634f;  // LOG2E folded into Q
#pragma unroll
    for (int c = 0; c < 6; ++c) {
      qf[c] = *(const half8*)&Qb[(size_t)qrow * 2304 + c * 16 + hi * 8];
#pragma unroll
      for (int e = 0; e < 8; ++e) qf[c][e] = qf[c][e] * s;
    }
  }

  // ---- hoisted staging offsets ----
  int ks_src[3], ks_dst[3];
#pragma unroll
  for (int j = 0; j < 3; ++j) {
    int s = j * 256 + t;
    int f = s >> 6, lane = s & 63;
    int sb = f / 6, c = f - sb * 6;
    ks_src[j] = (sb * 32 + (lane & 31)) * 2304 + c * 16 + ((lane >> 5) & 1) * 8;
    ks_dst[j] = s * 16;
  }
  bool vact[2];
  int v_src[2], v_dst[2][8];
#pragma unroll
  for (int j = 0; j < 2; ++j) {
    int u = j * 256 + t;
    vact[j] = u < 384;
    int kvp = u / 12, mm = u % 12;
    v_src[j] = 2 * kvp * 2304 + mm * 8;
#pragma unroll
    for (int e = 0; e < 8; ++e) {
      int d = mm * 8 + e;
      int sw = ((d & 7) ^ ((d >> 3) & 7)) << 3;
      v_dst[j][e] = d * 64 + ((2 * kvp) ^ sw);
    }
  }

  auto stage = [&](int kv0, int bi) {
    size_t goff = (size_t)kv0 * 2304;
#pragma unroll
    for (int j = 0; j < 3; ++j)
      gload_lds16(Kb + goff + ks_src[j], &KF[bi][ks_dst[j]]);
#pragma unroll
    for (int j = 0; j < 2; ++j)
      if (vact[j]) {
        const _Float16* vp = Vb + goff + v_src[j];
        half8 v0 = *(const half8*)vp;
        half8 v1 = *(const half8*)(vp + 2304);
#pragma unroll
        for (int e = 0; e < 8; ++e) {
          union { _Float16 h2[2]; unsigned u32; } pk;
          pk.h2[0] = v0[e]; pk.h2[1] = v1[e];
          *(unsigned*)&VF[bi][v_dst[j][e]] = pk.u32;
        }
      }
  };

  float m_run = -3.0e38f, l_run = 0.f;
  f32x16 oa[3] = {};  // O: col d = dt*32+lr, row q = (reg&3)+8*(reg>>2)+4*hi

  stage(0, 0);

  for (int tile = 0; tile < 16; ++tile) {
    int bi = tile & 1;
    __syncthreads();  // stage(tile) resident; compute(tile-1) done
    if (tile + 1 < 16) stage((tile + 1) * 64, bi ^ 1);

    // --- QK^T: S^T sub-tiles (kv subtile sb of 32) x full d=96
    f32x16 sA[2] = {};
#pragma unroll
    for (int sb = 0; sb < 2; ++sb)
#pragma unroll
      for (int c = 0; c < 6; ++c) {
        half8 kf = *(const half8*)(KF[bi] + (sb * 6 + c) * 1024 + l * 16);
        sA[sb] = __builtin_amdgcn_mfma_f32_32x32x16_f16(kf, qf[c], sA[sb], 0, 0, 0);
      }

    // --- softmax (log2 domain); lane owns q = lr; 32 vals in-lane + partner
    float tmax = -3.0e38f;
#pragma unroll
    for (int sb = 0; sb < 2; ++sb)
#pragma unroll
      for (int r = 0; r < 16; ++r) tmax = fmaxf(tmax, sA[sb][r]);
    tmax = fmaxf(tmax, __shfl_xor(tmax, 32, 64));

    if (!__all(tmax <= m_run + 11.5f)) {   // defer-max
      float m_new = fmaxf(m_run, tmax);
      float scale = __builtin_exp2f(m_run - m_new);
#pragma unroll
      for (int r = 0; r < 16; ++r) {
        float sr = __shfl(scale, (r & 3) + 8 * (r >> 2) + 4 * hi, 64);
        oa[0][r] *= sr; oa[1][r] *= sr; oa[2][r] *= sr;
      }
      l_run *= scale;
      m_run = m_new;
    }

    // --- P = exp2(S-m) with CONSTANT indices; pack; keep/send via hi-select.
    // Lane owns kv = (r&3)+8*(r>>2)+4*hi (+32*sb). Packed w32[p*2+m] covers
    // regs 4p+2m, +1. keep = w32[(2kb+hi)*2+m]; send = w32[(2kb+1-hi)*2+m]
    // (identical mapping to the verified R7 rk/rq, now branch-free selects).
    unsigned keep[8], send[8];  // idx = sb*4 + kb*2 + m
    float rs = 0.f;
#pragma unroll
    for (int sb = 0; sb < 2; ++sb) {
      float e[16];
#pragma unroll
      for (int r = 0; r < 16; ++r) {
        e[r] = __builtin_exp2f(sA[sb][r] - m_run);
        rs += e[r];
      }
      unsigned w32[8];
#pragma unroll
      for (int p = 0; p < 4; ++p)
#pragma unroll
        for (int m = 0; m < 2; ++m) {
          union { fp16x2 h2; unsigned u; } pk;
          pk.h2 = __builtin_amdgcn_cvt_pkrtz(e[4 * p + 2 * m], e[4 * p + 2 * m + 1]);
          w32[p * 2 + m] = pk.u;
        }
#pragma unroll
      for (int kb = 0; kb < 2; ++kb)
#pragma unroll
        for (int m = 0; m < 2; ++m) {
          keep[sb * 4 + kb * 2 + m] = hi ? w32[(2 * kb + 1) * 2 + m] : w32[(2 * kb) * 2 + m];
          send[sb * 4 + kb * 2 + m] = hi ? w32[(2 * kb) * 2 + m] : w32[(2 * kb + 1) * 2 + m];
        }
    }
    rs += __shfl_xor(rs, 32, 64);
    l_run += rs;

    unsigned recv[8];
#pragma unroll
    for (int i = 0; i < 8; ++i) recv[i] = __shfl_xor(send[i], 32, 64);

    // --- assemble PV A-frags and multiply against V fragments
#pragma unroll
    for (int kstep = 0; kstep < 4; ++kstep) {
      int base = (kstep >> 1) * 4 + (kstep & 1) * 2;
      union { unsigned u[4]; half8 h8; } pa;
      pa.u[0] = hi ? recv[base + 0] : keep[base + 0];
      pa.u[1] = hi ? recv[base + 1] : keep[base + 1];
      pa.u[2] = hi ? keep[base + 0] : recv[base + 0];
      pa.u[3] = hi ? keep[base + 1] : recv[base + 1];
#pragma unroll
      for (int dt = 0; dt < 3; ++dt) {
        int d = dt * 32 + lr;
        int sw = ((d & 7) ^ ((d >> 3) & 7)) << 3;
        half8 vf = *(const half8*)&VF[bi][d * 64 + ((kstep * 16 + hi * 8) ^ sw)];
        oa[dt] = __builtin_amdgcn_mfma_f32_32x32x16_f16(pa.h8, vf, oa[dt], 0, 0, 0);
      }
    }
  }

  // --- epilogue: O /= (l_run * sqrt(768))
  float inv = 1.0f / (l_run * 27.712812921102035f);
  size_t rbase = (size_t)(b * 1024 + qt * 128 + w * 32) * 768 + h * 96;
#pragma unroll
  for (int r = 0; r < 16; ++r) {
    int q = (r & 3) + 8 * (r >> 2) + 4 * hi;
    float ivr = __shfl(inv, q, 64);
#pragma unroll
    for (int dt = 0; dt < 3; ++dt)
      Oh[rbase + (size_t)q * 768 + dt * 32 + lr] = (_Float16)(oa[dt][r] * ivr);
  }
}

// ---------------- launch ----------------

extern "C" void kernel_launch(void* const* d_in, const int* in_sizes, int n_in,
                              void* d_out, int out_size, void* d_ws, size_t ws_size,
                              hipStream_t stream) {
  const float* x  = (const float*)d_in[0];
  const float* Wq = (const float*)d_in[1];
  const float* bq = (const float*)d_in[2];
  const float* Wk = (const float*)d_in[3];
  const float* bk = (const float*)d_in[4];
  const float* Wv = (const float*)d_in[5];
  const float* bv = (const float*)d_in[6];
  const float* Wo = (const float*)d_in[7];
  const float* bo = (const float*)d_in[8];
  float* out = (float*)d_out;

  char* ws = (char*)d_ws;
  _Float16* WT   = (_Float16*)(ws);                // 4,718,592 B
  float*    bias = (float*)(ws + 4718592);         // 9,216 B (padded to 32K)
  _Float16* xh   = (_Float16*)(ws + 4751360);      // 25,165,824 B
  _Float16* QKV  = (_Float16*)(ws + 29917184);     // 75,497,472 B
  _Float16* Oh   = (_Float16*)(ws + 105414656);    // 25,165,824 B  (total ~130.6 MB)

  conv_x_kernel<<<6144, 256, 0, stream>>>(x, xh);
  transpose_cvt_kernel<<<dim3(24, 24, 4), dim3(32, 8), 0, stream>>>(Wq, Wk, Wv, Wo, WT);
  conv_bias_kernel<<<9, 256, 0, stream>>>(bq, bk, bv, bias);

  // QKV: M=16384, N=2304, K=768 -> grid 64*9 = 576 (div by 8 for XCD swizzle)
  gemm256_kernel<1><<<576, 512, 0, stream>>>(xh, WT, bias, QKV, 16384, 2304, 768, 2304);

  attn_kernel<<<1024, 256, 0, stream>>>(QKV, Oh);

  // out-proj: M=16384, N=768, K=768 -> grid 64*3 = 192
  gemm256_kernel<0><<<192, 512, 0, stream>>>(Oh, WT + (size_t)2304 * 768, bo, out,
                                             16384, 768, 768, 768);
}